// Round 3
// baseline (300.971 us; speedup 1.0000x reference)
//
#include <hip/hip_runtime.h>

#define D 64

typedef __attribute__((ext_vector_type(8))) short short8;   // 8 bf16 = 4 VGPRs
typedef __attribute__((ext_vector_type(4))) float floatx4;  // MFMA C/D

__device__ __forceinline__ ushort f2bf(float f) {     // fp32 -> bf16, RNE
    unsigned u = __float_as_uint(f);
    u += 0x7fffu + ((u >> 16) & 1u);
    return (ushort)(u >> 16);
}
__device__ __forceinline__ float bf2f(ushort h) {
    return __int_as_float(((unsigned)h) << 16);
}

// ---------------- cast x to bf16 rows + zero cnt/cur + init hist/bincur0/total ----
__global__ void cast_kernel(const float* __restrict__ x, ushort* __restrict__ xh,
                            int* __restrict__ cnt, int* __restrict__ cur,
                            int* __restrict__ hist, int* __restrict__ bincur0,
                            int* __restrict__ total, int n4, int N) {
    int i = blockIdx.x * blockDim.x + threadIdx.x;
    if (i < N) { cnt[i] = 0; cur[i] = 0; }
    if (i < 64) { hist[i] = 0; bincur0[i] = 0; }
    if (i == 0) *total = 0;
    if (i >= n4) return;
    float4 v = ((const float4*)x)[i];
    ushort4 r;
    r.x = f2bf(v.x); r.y = f2bf(v.y); r.z = f2bf(v.z); r.w = f2bf(v.w);
    ((ushort4*)xh)[i] = r;
}

// ---------------- degree count: XCD-partitioned atomics --------------------------
// part p = bid & 7 (default bid->XCD round-robin); each part owns dst range
// [N*p/8, N*(p+1)/8): cnt lines are only touched by one XCD's L2.
// ei stream is read-once -> NON-TEMPORAL loads so it can't evict the hot
// cnt lines from L2 (round-2 lesson: streaming reads thrashed dirty lines).
__global__ void deg_kernel(const int* __restrict__ ei, int* __restrict__ cnt,
                           int N, int E) {
    int p = blockIdx.x & 7;
    int slice = blockIdx.x >> 3;
    int lo = (int)(((long long)N * p) >> 3);
    int hi = (int)(((long long)N * (p + 1)) >> 3);
    int e0 = slice * 8192;
#pragma unroll 4
    for (int it = 0; it < 32; ++it) {
        int e = e0 + it * 256 + threadIdx.x;
        if (e < E) {
            int dst = __builtin_nontemporal_load(ei + E + e);
            if (dst >= lo && dst < hi) atomicAdd(&cnt[dst], 1);
        }
    }
}

// ---------------- alloc: wave-scan of degrees -> beg, plus degree histogram -----
__global__ void alloc_kernel(const int* __restrict__ cnt, int* __restrict__ beg,
                             int* __restrict__ total, int* __restrict__ hist, int N) {
    __shared__ int lh[64];
    int tid = threadIdx.x;
    if (tid < 64) lh[tid] = 0;
    __syncthreads();
    int i = blockIdx.x * blockDim.x + tid;
    int lane = tid & 63;
    int c = (i < N) ? cnt[i] : 0;
    if (i < N) atomicAdd(&lh[c < 63 ? c : 63], 1);
    int p = c;
#pragma unroll
    for (int o = 1; o < 64; o <<= 1) {
        int u = __shfl_up(p, o, 64);
        if (lane >= o) p += u;
    }
    int wavetot = __shfl(p, 63, 64);
    int base = 0;
    if (lane == 63) base = atomicAdd(total, wavetot);
    base = __shfl(base, 63, 64);
    if (i < N) beg[i] = base + p - c;
    __syncthreads();
    if (tid < 64 && lh[tid] > 0) atomicAdd(&hist[tid], lh[tid]);
}

// ---------------- CSR fill: XCD-partitioned scatter ------------------------------
// srclist ranges of part-p nodes are written only by part-p blocks (one XCD):
// dirty lines stay L2-local. NON-TEMPORAL loads on the ei stream keep those
// ~550KB of hot lines (srclist part + cur part) resident until complete ->
// each line evicted once, not ~10x (round-2: WRITE_SIZE 40MB for a 4MB array).
__global__ void fill_kernel(const int* __restrict__ ei, const int* __restrict__ beg,
                            int* __restrict__ cur, int* __restrict__ srclist,
                            int N, int E) {
    int p = blockIdx.x & 7;
    int slice = blockIdx.x >> 3;
    int lo = (int)(((long long)N * p) >> 3);
    int hi = (int)(((long long)N * (p + 1)) >> 3);
    int e0 = slice * 8192;
#pragma unroll 4
    for (int it = 0; it < 32; ++it) {
        int e = e0 + it * 256 + threadIdx.x;
        if (e < E) {
            int dst = __builtin_nontemporal_load(ei + E + e);
            if (dst >= lo && dst < hi) {
                int src = __builtin_nontemporal_load(ei + e);
                int pos = beg[dst] + atomicAdd(&cur[dst], 1);
                srclist[pos] = src;
            }
        }
    }
}

// ---------------- scatter nodes into DESCENDING-degree perm ----------------------
__global__ void scatter_kernel(const int* __restrict__ cnt, const int* __restrict__ hist,
                               int* __restrict__ bincur0, int* __restrict__ perm, int N) {
    __shared__ int lh[64];
    __shared__ int lbase[64];
    __shared__ int sbase[64];
    int tid = threadIdx.x;
    if (tid < 64) {
        lh[tid] = 0;
        int c = hist[tid];
        int p = c;
#pragma unroll
        for (int o = 1; o < 64; o <<= 1) {
            int u = __shfl_up(p, o, 64);
            if (tid >= o) p += u;
        }
        sbase[tid] = N - p;            // suffix base: high-degree bins first
    }
    __syncthreads();
    int i = blockIdx.x * blockDim.x + tid;
    int bin = 0, slot = 0;
    if (i < N) {
        int c = cnt[i];
        bin = c < 63 ? c : 63;
        slot = atomicAdd(&lh[bin], 1);
    }
    __syncthreads();
    if (tid < 64 && lh[tid] > 0) lbase[tid] = sbase[tid] + atomicAdd(&bincur0[tid], lh[tid]);
    __syncthreads();
    if (i < N) perm[lbase[bin] + slot] = i;
}

// ---------------- fused SAGE layer: bf16 gather + MFMA combine ----------------
// 16 nodes per wave via degree-sorted perm (uniform degree -> md ~= deg).
// Epilogue stages the 16x64 tile in per-wave LDS, then writes FULL rows
// (128B bf16 / 256B fp32) -> no partial-line RMW at HBM/L2.
// launch_bounds(256,4): VGPR cap 128, compiler lands ~64, NO spill (the (256,8)
// cap of 64 forced scratch spills: +150MB traffic, do not repeat).

__global__ void __launch_bounds__(256, 4) sage_kernel(
    const ushort* __restrict__ inh,      // bf16 rows [N][64]
    const int* __restrict__ perm,
    const int* __restrict__ beg_, const int* __restrict__ cnt_,
    const int* __restrict__ srclist,
    const float* __restrict__ Wl, const float* __restrict__ bl,
    const float* __restrict__ Wr,
    float* __restrict__ out_f32,         // fp32 out (layer 2) or null
    ushort* __restrict__ out_bf,         // bf16 out (layer 1) or null
    int N, int relu) {
    __shared__ short8 fL[8][64];   // [c*2+s][lane]: B-frag of Wl^T, col-tile c, k-step s
    __shared__ short8 fR[8][64];
    __shared__ float ot[4][16 * 68];     // per-wave out tile, stride 68 (pad: bank spread)
    int tid = threadIdx.x;
    int lane = tid & 63;
    {
        int c = tid >> 6;
        int n = lane & 15;
        int q = lane >> 4;
#pragma unroll
        for (int s = 0; s < 2; ++s) {
            const float* pl = Wl + (c * 16 + n) * D + s * 32 + q * 8;
            const float* pr = Wr + (c * 16 + n) * D + s * 32 + q * 8;
            short8 vl, vr;
#pragma unroll
            for (int j = 0; j < 8; ++j) {
                vl[j] = (short)f2bf(pl[j]);
                vr[j] = (short)f2bf(pr[j]);
            }
            fL[c * 2 + s][lane] = vl;
            fR[c * 2 + s][lane] = vr;
        }
    }
    __syncthreads();

    int m = lane & 15;
    int q = lane >> 4;
    float* otw = &ot[tid >> 6][0];
    float b0 = bl[m], b1 = bl[16 + m], b2 = bl[32 + m], b3 = bl[48 + m];
    int gwave   = blockIdx.x * 4 + (tid >> 6);
    int nwaves  = gridDim.x * 4;
    int ngroups = (N + 15) >> 4;

    for (int g = gwave; g < ngroups; g += nwaves) {
        int base = g * 16;
        bool nv = (base + m) < N;
        int node = nv ? perm[base + m] : 0;
        int beg = nv ? beg_[node] : 0;   // 4 lanes per node share the address
        int deg = nv ? cnt_[node] : 0;

        // wave-max degree (uniform after descending sort except at bin boundaries)
        int md = deg;
        md = max(md, __shfl_xor(md, 1, 64));
        md = max(md, __shfl_xor(md, 2, 64));
        md = max(md, __shfl_xor(md, 4, 64));
        md = max(md, __shfl_xor(md, 8, 64));

        float f0[8], f1[8];
#pragma unroll
        for (int u = 0; u < 8; ++u) { f0[u] = 0.f; f1[u] = 0.f; }

#pragma unroll 8
        for (int j = 0; j < md; ++j) {
            int idx = beg + ((j < deg) ? j : 0);
            int si = srclist[idx];
            const ushort* rp = inh + (size_t)si * D;
            short8 lo = *(const short8*)(rp + q * 8);        // features q*8..+7
            short8 hi = *(const short8*)(rp + 32 + q * 8);   // features 32+q*8..+7
            float msk = (j < deg) ? 1.f : 0.f;
#pragma unroll
            for (int u = 0; u < 8; ++u) {
                f0[u] = fmaf(msk, bf2f((ushort)lo[u]), f0[u]);
                f1[u] = fmaf(msk, bf2f((ushort)hi[u]), f1[u]);
            }
        }

        float scale = (deg > 0) ? 1.0f / (float)deg : 0.0f;
        short8 a0, a1;
#pragma unroll
        for (int u = 0; u < 8; ++u) {
            a0[u] = (short)f2bf(f0[u] * scale);
            a1[u] = (short)f2bf(f1[u] * scale);
        }

        // root rows load directly as A-fragments
        const ushort* rr = inh + (size_t)node * D;
        short8 r0 = *(const short8*)(rr + q * 8);
        short8 r1 = *(const short8*)(rr + 32 + q * 8);

#pragma unroll
        for (int c = 0; c < 4; ++c) {
            float bc = (c == 0) ? b0 : (c == 1) ? b1 : (c == 2) ? b2 : b3;
            floatx4 acc = {bc, bc, bc, bc};
            acc = __builtin_amdgcn_mfma_f32_16x16x32_bf16(a0, fL[c * 2 + 0][lane], acc, 0, 0, 0);
            acc = __builtin_amdgcn_mfma_f32_16x16x32_bf16(a1, fL[c * 2 + 1][lane], acc, 0, 0, 0);
            acc = __builtin_amdgcn_mfma_f32_16x16x32_bf16(r0, fR[c * 2 + 0][lane], acc, 0, 0, 0);
            acc = __builtin_amdgcn_mfma_f32_16x16x32_bf16(r1, fR[c * 2 + 1][lane], acc, 0, 0, 0);
#pragma unroll
            for (int r = 0; r < 4; ++r) {
                float v = acc[r];
                if (relu) v = fmaxf(v, 0.f);
                otw[(q * 4 + r) * 68 + c * 16 + m] = v;   // stage in LDS (wave-private)
            }
        }

        // full-row writeout: 4 lanes per node row, line-complete stores
        int rho = lane >> 2;                 // node slot 0..15
        int q4  = lane & 3;                  // quarter of the row
        int onode = __shfl(node, rho, 64);
        const float* sp = &otw[rho * 68 + q4 * 16];
        if (base + rho < N) {
            if (out_bf) {
                uint u[8];
#pragma unroll
                for (int j = 0; j < 8; ++j)
                    u[j] = (uint)f2bf(sp[2 * j]) | ((uint)f2bf(sp[2 * j + 1]) << 16);
                uint4* dp = (uint4*)(out_bf + (size_t)onode * D + q4 * 16);
                uint4 w0 = {u[0], u[1], u[2], u[3]};
                uint4 w1 = {u[4], u[5], u[6], u[7]};
                dp[0] = w0; dp[1] = w1;      // 32B/lane, 128B/row contiguous
            } else {
                float4* dp = (float4*)(out_f32 + (size_t)onode * D + q4 * 16);
                const float4* s4 = (const float4*)sp;
                dp[0] = s4[0]; dp[1] = s4[1]; dp[2] = s4[2]; dp[3] = s4[3];  // 64B/lane
            }
        }
    }
}

extern "C" void kernel_launch(void* const* d_in, const int* in_sizes, int n_in,
                              void* d_out, int out_size, void* d_ws, size_t ws_size,
                              hipStream_t stream) {
    const float* x   = (const float*)d_in[0];
    const int*   ei  = (const int*)d_in[1];
    const float* W1l = (const float*)d_in[2];
    const float* b1l = (const float*)d_in[3];
    const float* W1r = (const float*)d_in[4];
    const float* W2l = (const float*)d_in[5];
    const float* b2l = (const float*)d_in[6];
    const float* W2r = (const float*)d_in[7];
    float* out = (float*)d_out;

    int N = in_sizes[0] / D;   // 100000
    int E = in_sizes[1] / 2;   // 1000000

    char* ws = (char*)d_ws;
    // Layout (bytes):
    //   [0, N*D*2)         xh : bf16 x rows
    //   [N*D*2, 2*N*D*2)   hh : bf16 h rows; fill-phase `cur` cursor aliases here
    //                          (N ints = 400KB < 12.8MB; dead before sage1 writes hh)
    //   then srclist (+slack), beg, cnt, perm, total, hist, bincur0
    ushort* xh = (ushort*)ws;
    ushort* hh = xh + (size_t)N * D;
    int*   cur     = (int*)hh;                            // N ints (alias hh)
    int*   srclist = (int*)(ws + (size_t)2 * N * D * 2);  // E ints + 64 slack
    int*   beg     = srclist + E + 64;                    // N ints
    int*   cnt     = beg + N;                             // N ints
    int*   perm    = cnt + N;                             // N ints
    int*   total   = perm + N;                            // 1 int
    int*   hist    = total + 1;                           // 64 ints
    int*   bincur0 = hist + 64;                           // 64 ints

    int n4 = N * D / 4;
    cast_kernel<<<(n4 + 255) / 256, 256, 0, stream>>>(x, xh, cnt, cur, hist,
                                                      bincur0, total, n4, N);

    int nblocks = (N + 255) / 256;
    int nslices = (E + 8191) / 8192;
    deg_kernel<<<nslices * 8, 256, 0, stream>>>(ei, cnt, N, E);
    alloc_kernel<<<nblocks, 256, 0, stream>>>(cnt, beg, total, hist, N);
    fill_kernel<<<nslices * 8, 256, 0, stream>>>(ei, beg, cur, srclist, N, E);
    scatter_kernel<<<nblocks, 256, 0, stream>>>(cnt, hist, bincur0, perm, N);

    int ngroups = (N + 15) / 16;              // 6250
    int sblocks = (ngroups + 3) / 4;          // 1 group per wave
    // layer 1: hh(bf16) = relu(mean_agg(xh)@W1l^T + b1l + xh@W1r^T)
    sage_kernel<<<sblocks, 256, 0, stream>>>(xh, perm, beg, cnt, srclist,
                                             W1l, b1l, W1r, nullptr, hh, N, 1);
    // layer 2: out(fp32) = mean_agg(hh)@W2l^T + b2l + hh@W2r^T
    sage_kernel<<<sblocks, 256, 0, stream>>>(hh, perm, beg, cnt, srclist,
                                             W2l, b2l, W2r, out, nullptr, N, 0);
}

// Round 4
// 223.281 us; speedup vs baseline: 1.3479x; 1.3479x over previous
//
#include <hip/hip_runtime.h>

#define D 64
#define BK_SHIFT 9
#define BK_MASK 511
#define SEGCAP 6144

typedef __attribute__((ext_vector_type(8))) short short8;   // 8 bf16 = 4 VGPRs
typedef __attribute__((ext_vector_type(4))) float floatx4;  // MFMA C/D

__device__ __forceinline__ ushort f2bf(float f) {     // fp32 -> bf16, RNE
    unsigned u = __float_as_uint(f);
    u += 0x7fffu + ((u >> 16) & 1u);
    return (ushort)(u >> 16);
}
__device__ __forceinline__ float bf2f(ushort h) {
    return __int_as_float(((unsigned)h) << 16);
}

// ---------------- cast x to bf16 rows + zero bkcnt/hist/bincur0 -------------------
__global__ void cast_kernel(const float* __restrict__ x, ushort* __restrict__ xh,
                            int* __restrict__ bkcnt, int* __restrict__ hist,
                            int* __restrict__ bincur0, int n4) {
    int i = blockIdx.x * blockDim.x + threadIdx.x;
    if (i < 256) bkcnt[i] = 0;
    if (i < 64) { hist[i] = 0; bincur0[i] = 0; }
    if (i >= n4) return;
    float4 v = ((const float4*)x)[i];
    ushort4 r;
    r.x = f2bf(v.x); r.y = f2bf(v.y); r.z = f2bf(v.z); r.w = f2bf(v.w);
    ((ushort4*)xh)[i] = r;
}

// ---------------- A1: per-block LDS hist of dst>>9 -> global bucket counts --------
// (round-3 lesson: scattered 4B stores/atomics pay ~8x HBM sector tax; counting
//  sort with LDS staging makes every HBM write line-complete)
__global__ void bkcount_kernel(const int* __restrict__ ei, int* __restrict__ bkcnt,
                               int E, int B) {
    __shared__ int h[256];
    int tid = threadIdx.x;
    h[tid] = 0;
    __syncthreads();
    int e0 = blockIdx.x * 8192;
#pragma unroll 4
    for (int it = 0; it < 32; ++it) {
        int e = e0 + it * 256 + tid;
        if (e < E) atomicAdd(&h[ei[E + e] >> BK_SHIFT], 1);
    }
    __syncthreads();
    if (tid < B && h[tid]) atomicAdd(&bkcnt[tid], h[tid]);
}

// ---------------- A2: single-block exclusive scan of bucket counts ----------------
__global__ void bkscan_kernel(const int* __restrict__ bkcnt, int* __restrict__ bkbeg,
                              int* __restrict__ bkcur, int B) {
    __shared__ int wsum[4];
    int tid = threadIdx.x;
    int lane = tid & 63, w = tid >> 6;
    int c = (tid < B) ? bkcnt[tid] : 0;
    int p = c;
#pragma unroll
    for (int o = 1; o < 64; o <<= 1) {
        int u = __shfl_up(p, o, 64);
        if (lane >= o) p += u;
    }
    if (lane == 63) wsum[w] = p;
    __syncthreads();
    int base = 0;
    for (int ww = 0; ww < w; ++ww) base += wsum[ww];
    int excl = base + p - c;
    if (tid < B) { bkbeg[tid] = excl; bkcur[tid] = excl; }
    if (tid == B - 1) bkbeg[B] = excl + c;   // == E
}

// ---------------- A3: route edges into bucket regions, packed (src<<9)|dstlow -----
// per (block,bucket) run is ~42 contiguous ints -> L2 merges into full lines.
__global__ void route_kernel(const int* __restrict__ ei, int* __restrict__ bkcur,
                             int* __restrict__ bucketed, int E, int B) {
    __shared__ int h[256];
    __shared__ int gb[256];
    int tid = threadIdx.x;
    h[tid] = 0;
    __syncthreads();
    int e0 = blockIdx.x * 8192;
#pragma unroll 4
    for (int it = 0; it < 32; ++it) {            // pass 1: local hist
        int e = e0 + it * 256 + tid;
        if (e < E) atomicAdd(&h[ei[E + e] >> BK_SHIFT], 1);
    }
    __syncthreads();
    if (tid < B) gb[tid] = h[tid] ? atomicAdd(&bkcur[tid], h[tid]) : 0;
    h[tid] = 0;                                  // reuse as pass-2 cursor (own slot)
    __syncthreads();
#pragma unroll 4
    for (int it = 0; it < 32; ++it) {            // pass 2: route (dst slice L2-hot)
        int e = e0 + it * 256 + tid;
        if (e < E) {
            int dst = ei[E + e];
            int key = dst >> BK_SHIFT;
            int src = ei[e];
            int r = atomicAdd(&h[key], 1);
            bucketed[gb[key] + r] = (src << BK_SHIFT) | (dst & BK_MASK);
        }
    }
}

// ---------------- B: per-bucket CSR segment build, all HBM writes coalesced -------
// block k owns nodes [k*512,(k+1)*512): LDS degree count -> 512-scan -> segment
// built in LDS -> coalesced dump. Emits beg/cnt (coalesced) + degree histogram.
__global__ void csr_kernel(const int* __restrict__ bucketed, const int* __restrict__ bkbeg,
                           int* __restrict__ srclist, int* __restrict__ beg,
                           int* __restrict__ cnt, int* __restrict__ hist, int N) {
    __shared__ int lcnt[512];
    __shared__ int lbeg[512];
    __shared__ int seg[SEGCAP];
    __shared__ int wsum[4];
    __shared__ int lh[64];
    int k = blockIdx.x;
    int tid = threadIdx.x;
    int nd0 = k << BK_SHIFT;
    int nn = min(512, N - nd0);
    int ebeg = bkbeg[k], eend = bkbeg[k + 1];
    int ecnt = eend - ebeg;
    lcnt[tid] = 0; lcnt[tid + 256] = 0;
    if (tid < 64) lh[tid] = 0;
    __syncthreads();
    for (int e = ebeg + tid; e < eend; e += 256)
        atomicAdd(&lcnt[bucketed[e] & BK_MASK], 1);
    __syncthreads();
    // exclusive 512-scan (2 elems/thread + wave combine)
    int a = lcnt[2 * tid], b = lcnt[2 * tid + 1];
    int s = a + b;
    int lane = tid & 63, w = tid >> 6;
    int p = s;
#pragma unroll
    for (int o = 1; o < 64; o <<= 1) {
        int u = __shfl_up(p, o, 64);
        if (lane >= o) p += u;
    }
    if (lane == 63) wsum[w] = p;
    __syncthreads();
    int base = 0;
    for (int ww = 0; ww < w; ++ww) base += wsum[ww];
    int excl = base + p - s;
    lbeg[2 * tid] = excl;
    lbeg[2 * tid + 1] = excl + a;
    lcnt[2 * tid] = 0; lcnt[2 * tid + 1] = 0;    // reuse as fill cursors
    __syncthreads();
    if (ecnt <= SEGCAP) {
        for (int e = ebeg + tid; e < eend; e += 256) {
            int v = bucketed[e];
            int key = v & BK_MASK;
            int pos = lbeg[key] + atomicAdd(&lcnt[key], 1);
            seg[pos] = v >> BK_SHIFT;
        }
        __syncthreads();
        for (int i = tid; i < ecnt; i += 256)
            srclist[ebeg + i] = seg[i];          // coalesced full-line dump
    } else {                                     // overflow fallback (correct, rare)
        for (int e = ebeg + tid; e < eend; e += 256) {
            int v = bucketed[e];
            int key = v & BK_MASK;
            int pos = lbeg[key] + atomicAdd(&lcnt[key], 1);
            srclist[ebeg + pos] = v >> BK_SHIFT;
        }
    }
    __syncthreads();
    for (int i = tid; i < nn; i += 256) {
        int dg = lcnt[i];                        // cursor end == degree
        cnt[nd0 + i] = dg;
        beg[nd0 + i] = ebeg + lbeg[i];
        atomicAdd(&lh[dg < 63 ? dg : 63], 1);
    }
    __syncthreads();
    if (tid < 64 && lh[tid]) atomicAdd(&hist[tid], lh[tid]);
}

// ---------------- scatter nodes into DESCENDING-degree perm ----------------------
__global__ void scatter_kernel(const int* __restrict__ cnt, const int* __restrict__ hist,
                               int* __restrict__ bincur0, int* __restrict__ perm, int N) {
    __shared__ int lh[64];
    __shared__ int lbase[64];
    __shared__ int sbase[64];
    int tid = threadIdx.x;
    if (tid < 64) {
        lh[tid] = 0;
        int c = hist[tid];
        int p = c;
#pragma unroll
        for (int o = 1; o < 64; o <<= 1) {
            int u = __shfl_up(p, o, 64);
            if (tid >= o) p += u;
        }
        sbase[tid] = N - p;            // suffix base: high-degree bins first
    }
    __syncthreads();
    int i = blockIdx.x * blockDim.x + tid;
    int bin = 0, slot = 0;
    if (i < N) {
        int c = cnt[i];
        bin = c < 63 ? c : 63;
        slot = atomicAdd(&lh[bin], 1);
    }
    __syncthreads();
    if (tid < 64 && lh[tid] > 0) lbase[tid] = sbase[tid] + atomicAdd(&bincur0[tid], lh[tid]);
    __syncthreads();
    if (i < N) perm[lbase[bin] + slot] = i;
}

// ---------------- fused SAGE layer: bf16 gather + MFMA combine ----------------
// 16 nodes per wave via degree-sorted perm (uniform degree -> md ~= deg).
// Epilogue stages the 16x64 tile in per-wave LDS, then writes FULL rows
// (128B bf16 / 256B fp32) -> no partial-line RMW at HBM/L2.
// launch_bounds(256,4): VGPR cap 128, compiler lands ~64, NO spill (the (256,8)
// cap of 64 forced scratch spills: +150MB traffic, do not repeat).

__global__ void __launch_bounds__(256, 4) sage_kernel(
    const ushort* __restrict__ inh,      // bf16 rows [N][64]
    const int* __restrict__ perm,
    const int* __restrict__ beg_, const int* __restrict__ cnt_,
    const int* __restrict__ srclist,
    const float* __restrict__ Wl, const float* __restrict__ bl,
    const float* __restrict__ Wr,
    float* __restrict__ out_f32,         // fp32 out (layer 2) or null
    ushort* __restrict__ out_bf,         // bf16 out (layer 1) or null
    int N, int relu) {
    __shared__ short8 fL[8][64];   // [c*2+s][lane]: B-frag of Wl^T, col-tile c, k-step s
    __shared__ short8 fR[8][64];
    __shared__ float ot[4][16 * 68];     // per-wave out tile, stride 68 (pad: bank spread)
    int tid = threadIdx.x;
    int lane = tid & 63;
    {
        int c = tid >> 6;
        int n = lane & 15;
        int q = lane >> 4;
#pragma unroll
        for (int s = 0; s < 2; ++s) {
            const float* pl = Wl + (c * 16 + n) * D + s * 32 + q * 8;
            const float* pr = Wr + (c * 16 + n) * D + s * 32 + q * 8;
            short8 vl, vr;
#pragma unroll
            for (int j = 0; j < 8; ++j) {
                vl[j] = (short)f2bf(pl[j]);
                vr[j] = (short)f2bf(pr[j]);
            }
            fL[c * 2 + s][lane] = vl;
            fR[c * 2 + s][lane] = vr;
        }
    }
    __syncthreads();

    int m = lane & 15;
    int q = lane >> 4;
    float* otw = &ot[tid >> 6][0];
    float b0 = bl[m], b1 = bl[16 + m], b2 = bl[32 + m], b3 = bl[48 + m];
    int gwave   = blockIdx.x * 4 + (tid >> 6);
    int nwaves  = gridDim.x * 4;
    int ngroups = (N + 15) >> 4;

    for (int g = gwave; g < ngroups; g += nwaves) {
        int base = g * 16;
        bool nv = (base + m) < N;
        int node = nv ? perm[base + m] : 0;
        int beg = nv ? beg_[node] : 0;   // 4 lanes per node share the address
        int deg = nv ? cnt_[node] : 0;

        // wave-max degree (uniform after descending sort except at bin boundaries)
        int md = deg;
        md = max(md, __shfl_xor(md, 1, 64));
        md = max(md, __shfl_xor(md, 2, 64));
        md = max(md, __shfl_xor(md, 4, 64));
        md = max(md, __shfl_xor(md, 8, 64));

        float f0[8], f1[8];
#pragma unroll
        for (int u = 0; u < 8; ++u) { f0[u] = 0.f; f1[u] = 0.f; }

#pragma unroll 8
        for (int j = 0; j < md; ++j) {
            int idx = beg + ((j < deg) ? j : 0);
            int si = srclist[idx];
            const ushort* rp = inh + (size_t)si * D;
            short8 lo = *(const short8*)(rp + q * 8);        // features q*8..+7
            short8 hi = *(const short8*)(rp + 32 + q * 8);   // features 32+q*8..+7
            float msk = (j < deg) ? 1.f : 0.f;
#pragma unroll
            for (int u = 0; u < 8; ++u) {
                f0[u] = fmaf(msk, bf2f((ushort)lo[u]), f0[u]);
                f1[u] = fmaf(msk, bf2f((ushort)hi[u]), f1[u]);
            }
        }

        float scale = (deg > 0) ? 1.0f / (float)deg : 0.0f;
        short8 a0, a1;
#pragma unroll
        for (int u = 0; u < 8; ++u) {
            a0[u] = (short)f2bf(f0[u] * scale);
            a1[u] = (short)f2bf(f1[u] * scale);
        }

        // root rows load directly as A-fragments
        const ushort* rr = inh + (size_t)node * D;
        short8 r0 = *(const short8*)(rr + q * 8);
        short8 r1 = *(const short8*)(rr + 32 + q * 8);

#pragma unroll
        for (int c = 0; c < 4; ++c) {
            float bc = (c == 0) ? b0 : (c == 1) ? b1 : (c == 2) ? b2 : b3;
            floatx4 acc = {bc, bc, bc, bc};
            acc = __builtin_amdgcn_mfma_f32_16x16x32_bf16(a0, fL[c * 2 + 0][lane], acc, 0, 0, 0);
            acc = __builtin_amdgcn_mfma_f32_16x16x32_bf16(a1, fL[c * 2 + 1][lane], acc, 0, 0, 0);
            acc = __builtin_amdgcn_mfma_f32_16x16x32_bf16(r0, fR[c * 2 + 0][lane], acc, 0, 0, 0);
            acc = __builtin_amdgcn_mfma_f32_16x16x32_bf16(r1, fR[c * 2 + 1][lane], acc, 0, 0, 0);
#pragma unroll
            for (int r = 0; r < 4; ++r) {
                float v = acc[r];
                if (relu) v = fmaxf(v, 0.f);
                otw[(q * 4 + r) * 68 + c * 16 + m] = v;   // stage in LDS (wave-private)
            }
        }

        // full-row writeout: 4 lanes per node row, line-complete stores
        int rho = lane >> 2;                 // node slot 0..15
        int q4  = lane & 3;                  // quarter of the row
        int onode = __shfl(node, rho, 64);
        const float* sp = &otw[rho * 68 + q4 * 16];
        if (base + rho < N) {
            if (out_bf) {
                uint u[8];
#pragma unroll
                for (int j = 0; j < 8; ++j)
                    u[j] = (uint)f2bf(sp[2 * j]) | ((uint)f2bf(sp[2 * j + 1]) << 16);
                uint4* dp = (uint4*)(out_bf + (size_t)onode * D + q4 * 16);
                uint4 w0 = {u[0], u[1], u[2], u[3]};
                uint4 w1 = {u[4], u[5], u[6], u[7]};
                dp[0] = w0; dp[1] = w1;      // 32B/lane, 128B/row contiguous
            } else {
                float4* dp = (float4*)(out_f32 + (size_t)onode * D + q4 * 16);
                const float4* s4 = (const float4*)sp;
                dp[0] = s4[0]; dp[1] = s4[1]; dp[2] = s4[2]; dp[3] = s4[3];  // 64B/lane
            }
        }
    }
}

extern "C" void kernel_launch(void* const* d_in, const int* in_sizes, int n_in,
                              void* d_out, int out_size, void* d_ws, size_t ws_size,
                              hipStream_t stream) {
    const float* x   = (const float*)d_in[0];
    const int*   ei  = (const int*)d_in[1];
    const float* W1l = (const float*)d_in[2];
    const float* b1l = (const float*)d_in[3];
    const float* W1r = (const float*)d_in[4];
    const float* W2l = (const float*)d_in[5];
    const float* b2l = (const float*)d_in[6];
    const float* W2r = (const float*)d_in[7];
    float* out = (float*)d_out;

    int N = in_sizes[0] / D;   // 100000
    int E = in_sizes[1] / 2;   // 1000000
    int B = (N + BK_MASK) >> BK_SHIFT;   // 196 buckets

    char* ws = (char*)d_ws;
    // Layout (bytes):
    //   [0, N*D*2)         xh : bf16 x rows
    //   [N*D*2, 2*N*D*2)   hh : bf16 h rows; `bucketed` (E ints = 4MB < 12.8MB)
    //                          aliases here -- dead before sage1 writes hh
    //   then srclist (+slack), beg, cnt, perm, hist, bincur0, bkcnt, bkbeg, bkcur
    ushort* xh = (ushort*)ws;
    ushort* hh = xh + (size_t)N * D;
    int*   bucketed = (int*)hh;                           // E ints (alias hh)
    int*   srclist  = (int*)(ws + (size_t)2 * N * D * 2); // E ints + 64 slack
    int*   beg      = srclist + E + 64;                   // N ints
    int*   cnt      = beg + N;                            // N ints
    int*   perm     = cnt + N;                            // N ints
    int*   hist     = perm + N;                           // 64 ints
    int*   bincur0  = hist + 64;                          // 64 ints
    int*   bkcnt    = bincur0 + 64;                       // 256 ints
    int*   bkbeg    = bkcnt + 256;                        // 257 ints
    int*   bkcur    = bkbeg + 257;                        // 256 ints

    int n4 = N * D / 4;
    cast_kernel<<<(n4 + 255) / 256, 256, 0, stream>>>(x, xh, bkcnt, hist, bincur0, n4);

    int nblocks = (N + 255) / 256;
    int eslices = (E + 8191) / 8192;
    bkcount_kernel<<<eslices, 256, 0, stream>>>(ei, bkcnt, E, B);
    bkscan_kernel<<<1, 256, 0, stream>>>(bkcnt, bkbeg, bkcur, B);
    route_kernel<<<eslices, 256, 0, stream>>>(ei, bkcur, bucketed, E, B);
    csr_kernel<<<B, 256, 0, stream>>>(bucketed, bkbeg, srclist, beg, cnt, hist, N);
    scatter_kernel<<<nblocks, 256, 0, stream>>>(cnt, hist, bincur0, perm, N);

    int ngroups = (N + 15) / 16;              // 6250
    int sblocks = (ngroups + 3) / 4;          // 1 group per wave
    // layer 1: hh(bf16) = relu(mean_agg(xh)@W1l^T + b1l + xh@W1r^T)
    sage_kernel<<<sblocks, 256, 0, stream>>>(xh, perm, beg, cnt, srclist,
                                             W1l, b1l, W1r, nullptr, hh, N, 1);
    // layer 2: out(fp32) = mean_agg(hh)@W2l^T + b2l + hh@W2r^T
    sage_kernel<<<sblocks, 256, 0, stream>>>(hh, perm, beg, cnt, srclist,
                                             W2l, b2l, W2r, out, nullptr, N, 0);
}